// Round 10
// baseline (43434.036 us; speedup 1.0000x reference)
//
#include <hip/hip_runtime.h>

typedef unsigned int u32;
typedef unsigned long long u64;
typedef float f32x4 __attribute__((ext_vector_type(4)));

// np-bit-exact Leaky update: m' = f32(f32(f32(0.95f*m) + cur) - reset)
// reset from PREVIOUS mem; (mem-1>0) === (mem>1) exactly in f32 (Sterbenz).
__device__ __forceinline__ float leaky(float m, float cur) {
  float r = (m > 1.0f) ? 1.0f : 0.0f;
  return __fsub_rn(__fadd_rn(__fmul_rn(0.95f, m), cur), r);
}

// ---------------------------------------------------------------------------
// Phase A: cur1 (exact FMA chain, d ascending) + layer-1 sim; emit per-step
// spike bitmasks to global in [t][kw][sample] layout.  (unchanged — verified)
// ---------------------------------------------------------------------------
__global__ __launch_bounds__(256) void k_spk1(
    const float* __restrict__ x, const float* __restrict__ W1,
    const float* __restrict__ b1, u32* __restrict__ masks,
    int s0, int Sc) {
  __shared__ float w1s[8 * 1024];
  const int tid = threadIdx.x, lane = tid & 63, w = tid >> 6;
  const int sl = blockIdx.x * 4 + w;
  const size_t s = (size_t)s0 + sl;

  float c1[16];
#pragma unroll
  for (int j = 0; j < 16; ++j) c1[j] = 0.0f;
#pragma unroll 1
  for (int ch = 0; ch < 8; ++ch) {
    __syncthreads();
#pragma unroll
    for (int it = 0; it < 8; ++it) {
      int v = tid + it * 256;
      *(f32x4*)(w1s + v * 4) =
          *(const f32x4*)(W1 + (size_t)(ch * 8 + (v >> 8)) * 1024 + (v & 255) * 4);
    }
    __syncthreads();
#pragma unroll 1
    for (int dl = 0; dl < 8; ++dl) {
      float xv = x[s * 64 + ch * 8 + dl];
#pragma unroll
      for (int j = 0; j < 16; ++j)
        c1[j] = fmaf(xv, w1s[dl * 1024 + j * 64 + lane], c1[j]);
    }
  }
#pragma unroll
  for (int j = 0; j < 16; ++j) c1[j] = __fadd_rn(c1[j], b1[j * 64 + lane]);

  float m1[16];
#pragma unroll
  for (int j = 0; j < 16; ++j) m1[j] = 0.0f;

#pragma unroll 1
  for (int t = 0; t < 25; ++t) {
#pragma unroll
    for (int j = 0; j < 16; ++j) {
      m1[j] = leaky(m1[j], c1[j]);
      u64 ball = __ballot(m1[j] > 1.0f);
      if (lane == 0) {
        masks[((size_t)t * 32 + 2 * j) * Sc + sl] = (u32)ball;
        masks[((size_t)t * 32 + 2 * j + 1) * Sc + sl] = (u32)(ball >> 32);
      }
    }
  }
}

// ---------------------------------------------------------------------------
// Phase B: cur2, 16 samples x 1 step per wave — r8's verified gate/FMA core
// (88-VGPR form, VALUBusy 64%) with ROUND-10 CHANGE: block-shared LDS-staged
// W2 stream. Every task streams the SAME rows 0..1023, so the block's 4
// waves share one staged copy: L2->L1 traffic /4 (205->51 GB) and load
// latency moves to block-level double-buffered staging (T14 split: loads
// issued at tile top, ds_writes after the 4096-cy compute, 1 barrier/tile).
// r9 lesson honored: NO extra per-wave prefetch registers — latency hiding
// comes from the shared LDS pipeline, keeping ~2 waves/SIMD resident.
// Arithmetic unchanged (verified r5-r8): k-ascending acc = fmaf(g, w, acc),
// g = wave-uniform (bit ? 1.0f : 0.0f): fma(1,w,c)=RN add = BLAS step,
// fma(0,w,c)=c exactly. Accumulators = named scalar floats (arch-VGPR form).
// ---------------------------------------------------------------------------
#define FOR16(M) M(0) M(1) M(2) M(3) M(4) M(5) M(6) M(7) \
                 M(8) M(9) M(10) M(11) M(12) M(13) M(14) M(15)
#define FOR16A1(M, a) M(0,a) M(1,a) M(2,a) M(3,a) M(4,a) M(5,a) M(6,a) M(7,a) \
                      M(8,a) M(9,a) M(10,a) M(11,a) M(12,a) M(13,a) M(14,a) M(15,a)

#define DECL_ACC(i)                                                     \
  float aA##i##_0 = 0.f, aA##i##_1 = 0.f, aA##i##_2 = 0.f, aA##i##_3 = 0.f; \
  float aB##i##_0 = 0.f, aB##i##_1 = 0.f, aB##i##_2 = 0.f, aB##i##_3 = 0.f;

#define DECL_W(i) u32 w##i;
#define LOADW(i)  w##i = (u32)__builtin_amdgcn_readfirstlane((int)mp[i]);

#define GSQ(i, MB) { const float g = (w##i & (MB)) ? 1.0f : 0.0f;       \
  aA##i##_0 = fmaf(g, q0[0], aA##i##_0); aA##i##_1 = fmaf(g, q0[1], aA##i##_1); \
  aA##i##_2 = fmaf(g, q0[2], aA##i##_2); aA##i##_3 = fmaf(g, q0[3], aA##i##_3); \
  aB##i##_0 = fmaf(g, q1[0], aB##i##_0); aB##i##_1 = fmaf(g, q1[1], aB##i##_1); \
  aB##i##_2 = fmaf(g, q1[2], aB##i##_2); aB##i##_3 = fmaf(g, q1[3], aB##i##_3); }

#define STORE16(i) {                                                    \
  float* op = cur2 + ((size_t)(sl0 + i) * 25 + t) * 512 + lq;           \
  op[0] = __fadd_rn(aA##i##_0, bv0); op[1] = __fadd_rn(aA##i##_1, bv1); \
  op[2] = __fadd_rn(aA##i##_2, bv2); op[3] = __fadd_rn(aA##i##_3, bv3); \
  op[256] = __fadd_rn(aB##i##_0, bv4); op[257] = __fadd_rn(aB##i##_1, bv5); \
  op[258] = __fadd_rn(aB##i##_2, bv6); op[259] = __fadd_rn(aB##i##_3, bv7); }

__global__ __launch_bounds__(256) void k_cur2(
    const float* __restrict__ W2, const float* __restrict__ b2,
    const u32* __restrict__ masks, float* __restrict__ cur2, int Sc) {
  __shared__ float w2s[2][16][512];       // 64 KB double-buffered row tiles
  const int tid = threadIdx.x, lane = tid & 63, w = tid >> 6;
  const int task = blockIdx.x * 4 + w;    // grid = (Sc/16)*25/4 blocks
  const int grp = task / 25, t = task - grp * 25;
  const int sl0 = grp * 16;
  const int lq = lane * 4;

  FOR16(DECL_ACC)
  FOR16(DECL_W)
  f32x4 st[8];                            // staging regs (short-lived each tile)

  // prologue: stage tile 0 into buffer 0 (8192 floats, linear, coalesced)
  {
    const float* gsrc = W2 + tid * 4;
#pragma unroll
    for (int it = 0; it < 8; ++it) st[it] = *(const f32x4*)(gsrc + it * 1024);
    float* dst = &w2s[0][0][0] + tid * 4;
#pragma unroll
    for (int it = 0; it < 8; ++it) *(f32x4*)(dst + it * 1024) = st[it];
  }
  __syncthreads();

#pragma unroll 1
  for (int tile = 0; tile < 64; ++tile) {
    const float* cb = (tile & 1) ? &w2s[1][0][0] : &w2s[0][0][0];
    float* nb = (tile & 1) ? &w2s[0][0][0] : &w2s[1][0][0];

    // T14 issue-early: next tile's global loads in flight during compute
    if (tile < 63) {
      const float* gsrc = W2 + (size_t)(tile + 1) * 8192 + tid * 4;
#pragma unroll
      for (int it = 0; it < 8; ++it) st[it] = *(const f32x4*)(gsrc + it * 1024);
    }

    const int kw = tile >> 1;
    if (!(tile & 1)) {                    // new mask word every 2 tiles
      const u32* mp = masks + ((size_t)t * 32 + kw) * Sc + sl0;
      FOR16(LOADW)
    }
    const int hb = (tile & 1) * 16;       // bit offset within word kw

    // compute 16 rows from LDS (k = tile*16 + r, strictly ascending)
#pragma unroll
    for (int r = 0; r < 16; ++r) {
      const f32x4 q0 = *(const f32x4*)(cb + r * 512 + lq);
      const f32x4 q1 = *(const f32x4*)(cb + r * 512 + 256 + lq);
      const u32 mb = 1u << (hb + r);
      FOR16A1(GSQ, mb)
    }

    // T14 write-late: staged data lands in the other buffer before barrier
    if (tile < 63) {
      float* dst = nb + tid * 4;
#pragma unroll
      for (int it = 0; it < 8; ++it) *(f32x4*)(dst + it * 1024) = st[it];
    }
    __syncthreads();
  }

  const float bv0 = b2[lq], bv1 = b2[lq + 1], bv2 = b2[lq + 2], bv3 = b2[lq + 3];
  const float bv4 = b2[256 + lq], bv5 = b2[257 + lq];
  const float bv6 = b2[258 + lq], bv7 = b2[259 + lq];
  FOR16(STORE16)
}

// ---------------------------------------------------------------------------
// Phase C: layers 2-3 recurrence off stored cur2 (exact f32 round-trip).
// (unchanged — verified)
// ---------------------------------------------------------------------------
__global__ __launch_bounds__(256) void k_tail(
    const float* __restrict__ cur2, const float* __restrict__ W3,
    const float* __restrict__ b3, float* __restrict__ out, int s0, int Sc) {
  __shared__ float w3s[512];
  const int tid = threadIdx.x, lane = tid & 63, w = tid >> 6;
  const int sl = blockIdx.x * 4 + w;
  for (int i = tid; i < 512; i += 256) w3s[i] = W3[i];
  __syncthreads();

  float m2[8];
#pragma unroll
  for (int j = 0; j < 8; ++j) m2[j] = 0.0f;
  float m3 = 0.0f;
  double s3 = 0.0;
  const float b3v = b3[0];
  const float* cp = cur2 + (size_t)sl * 25 * 512;

#pragma unroll 1
  for (int t = 0; t < 25; ++t) {
    u64 s2b[8];
#pragma unroll
    for (int j = 0; j < 8; ++j) {
      float cur = cp[t * 512 + j * 64 + lane];
      m2[j] = leaky(m2[j], cur);
      s2b[j] = __ballot(m2[j] > 1.0f);
    }
    if (lane == 0) {
      float c3 = 0.0f;
#pragma unroll 1
      for (int j = 0; j < 8; ++j) {
        u64 mm = s2b[j];
        const int nb = j * 64;
        if (mm) {
          int nn = __ffsll(mm) - 1;
          mm &= mm - 1;
          float wv = w3s[nb + nn];
          while (mm) {
            int n2 = __ffsll(mm) - 1;
            mm &= mm - 1;
            float wn = w3s[nb + n2];   // next load issued before dependent add
            c3 = __fadd_rn(c3, wv);
            wv = wn;
          }
          c3 = __fadd_rn(c3, wv);
        }
      }
      c3 = __fadd_rn(c3, b3v);
      m3 = leaky(m3, c3);
      s3 += (double)m3;
    }
  }
  if (lane == 0) {
    double z = s3 / 25.0;
    out[s0 + sl] = (float)(1.0 / (1.0 + exp(-z)));
  }
}

// ---------------------------------------------------------------------------
// Fallback: original verified single-kernel path (used if workspace too small)
// ---------------------------------------------------------------------------
__global__ __launch_bounds__(256) void k_snn(
    const float* __restrict__ x, const float* __restrict__ W1,
    const float* __restrict__ b1, const float* __restrict__ W2,
    const float* __restrict__ b2, const float* __restrict__ W3,
    const float* __restrict__ b3, float* __restrict__ out) {
  __shared__ float w1s[8 * 1024];
  __shared__ float w3s[512];
  __shared__ u32 spkm[4][32];
  const int tid = threadIdx.x, lane = tid & 63, w = tid >> 6;
  const size_t s = (size_t)blockIdx.x * 4 + w;

  for (int i = tid; i < 512; i += 256) w3s[i] = W3[i];

  float c1[16];
#pragma unroll
  for (int j = 0; j < 16; ++j) c1[j] = 0.0f;
#pragma unroll 1
  for (int ch = 0; ch < 8; ++ch) {
    __syncthreads();
#pragma unroll
    for (int it = 0; it < 8; ++it) {
      int v = tid + it * 256;
      *(f32x4*)(w1s + v * 4) =
          *(const f32x4*)(W1 + (size_t)(ch * 8 + (v >> 8)) * 1024 + (v & 255) * 4);
    }
    __syncthreads();
#pragma unroll 1
    for (int dl = 0; dl < 8; ++dl) {
      float xv = x[s * 64 + ch * 8 + dl];
#pragma unroll
      for (int j = 0; j < 16; ++j)
        c1[j] = fmaf(xv, w1s[dl * 1024 + j * 64 + lane], c1[j]);
    }
  }
#pragma unroll
  for (int j = 0; j < 16; ++j) c1[j] = __fadd_rn(c1[j], b1[j * 64 + lane]);

  float m1[16];
#pragma unroll
  for (int j = 0; j < 16; ++j) m1[j] = 0.0f;
  float m2[8];
#pragma unroll
  for (int j = 0; j < 8; ++j) m2[j] = 0.0f;
  float b2l[8];
#pragma unroll
  for (int j = 0; j < 8; ++j) b2l[j] = b2[j * 64 + lane];
  const float b3v = b3[0];
  float m3 = 0.0f;
  double s3 = 0.0;

#pragma unroll 1
  for (int t = 0; t < 25; ++t) {
#pragma unroll
    for (int j = 0; j < 16; ++j) {
      m1[j] = leaky(m1[j], c1[j]);
      u64 ball = __ballot(m1[j] > 1.0f);
      if (lane == 0) {
        spkm[w][2 * j]     = (u32)ball;
        spkm[w][2 * j + 1] = (u32)(ball >> 32);
      }
    }
    __syncthreads();

    float c2[8];
#pragma unroll
    for (int j = 0; j < 8; ++j) c2[j] = 0.0f;
#pragma unroll 1
    for (int kw = 0; kw < 32; ++kw) {
      u32 mask = spkm[w][kw];
      int kbase = kw * 32;
      while (mask) {
        int kk = __ffs(mask) - 1;
        mask &= mask - 1;
        const float* wr = W2 + (size_t)(kbase + kk) * 512;
#pragma unroll
        for (int j = 0; j < 8; ++j)
          c2[j] = __fadd_rn(c2[j], wr[j * 64 + lane]);
      }
    }
    u64 s2b[8];
#pragma unroll
    for (int j = 0; j < 8; ++j) {
      float cur = __fadd_rn(c2[j], b2l[j]);
      m2[j] = leaky(m2[j], cur);
      s2b[j] = __ballot(m2[j] > 1.0f);
    }

    if (lane == 0) {
      float c3 = 0.0f;
#pragma unroll 1
      for (int j = 0; j < 8; ++j) {
        u64 mm = s2b[j];
        int nb = j * 64;
        while (mm) {
          int nn = __ffsll(mm) - 1;
          mm &= mm - 1;
          c3 = __fadd_rn(c3, w3s[nb + nn]);
        }
      }
      c3 = __fadd_rn(c3, b3v);
      m3 = leaky(m3, c3);
      s3 += (double)m3;
    }
    __syncthreads();
  }

  if (lane == 0) {
    double z = s3 / 25.0;
    out[s] = (float)(1.0 / (1.0 + exp(-z)));
  }
}

extern "C" void kernel_launch(void* const* d_in, const int* in_sizes, int n_in,
                              void* d_out, int out_size, void* d_ws, size_t ws_size,
                              hipStream_t stream) {
  const float* x  = (const float*)d_in[0];
  const float* W1 = (const float*)d_in[1];
  const float* b1 = (const float*)d_in[2];
  const float* W2 = (const float*)d_in[3];
  const float* b2 = (const float*)d_in[4];
  const float* W3 = (const float*)d_in[5];
  const float* b3 = (const float*)d_in[6];
  float* out = (float*)d_out;

  // Per-sample workspace: masks 25*32*4 = 3200 B, cur2 25*512*4 = 51200 B.
  const long long per_sample = 54400;
  long long smax = (d_ws != nullptr) ? (long long)(ws_size / per_sample) : 0;
  long long scap = smax > 65536 ? 65536 : smax;
  int S = (int)(scap & ~63LL);

  if (S >= 256) {
    u32* masks = (u32*)d_ws;
    float* cur2 = (float*)((char*)d_ws + (size_t)S * 3200);
    for (int s0 = 0; s0 < 65536; s0 += S) {
      int Sc = (65536 - s0 < S) ? (65536 - s0) : S;
      hipLaunchKernelGGL(k_spk1, dim3(Sc / 4), dim3(256), 0, stream,
                         x, W1, b1, masks, s0, Sc);
      hipLaunchKernelGGL(k_cur2, dim3(((Sc / 16) * 25) / 4), dim3(256), 0, stream,
                         W2, b2, masks, cur2, Sc);
      hipLaunchKernelGGL(k_tail, dim3(Sc / 4), dim3(256), 0, stream,
                         cur2, W3, b3, out, s0, Sc);
    }
  } else {
    hipLaunchKernelGGL(k_snn, dim3(16384), dim3(256), 0, stream,
                       x, W1, b1, W2, b2, W3, b3, out);
  }
}

// Round 11
// 26533.618 us; speedup vs baseline: 1.6369x; 1.6369x over previous
//
#include <hip/hip_runtime.h>

typedef unsigned int u32;
typedef unsigned long long u64;
typedef float f32x4 __attribute__((ext_vector_type(4)));

// np-bit-exact Leaky update: m' = f32(f32(f32(0.95f*m) + cur) - reset)
// reset from PREVIOUS mem; (mem-1>0) === (mem>1) exactly in f32 (Sterbenz).
__device__ __forceinline__ float leaky(float m, float cur) {
  float r = (m > 1.0f) ? 1.0f : 0.0f;
  return __fsub_rn(__fadd_rn(__fmul_rn(0.95f, m), cur), r);
}

// ---------------------------------------------------------------------------
// Phase A: cur1 (exact FMA chain, d ascending) + layer-1 sim; emit per-step
// spike bitmasks to global in [t][kw][sample] layout.  (unchanged — verified)
// ---------------------------------------------------------------------------
__global__ __launch_bounds__(256) void k_spk1(
    const float* __restrict__ x, const float* __restrict__ W1,
    const float* __restrict__ b1, u32* __restrict__ masks,
    int s0, int Sc) {
  __shared__ float w1s[8 * 1024];
  const int tid = threadIdx.x, lane = tid & 63, w = tid >> 6;
  const int sl = blockIdx.x * 4 + w;
  const size_t s = (size_t)s0 + sl;

  float c1[16];
#pragma unroll
  for (int j = 0; j < 16; ++j) c1[j] = 0.0f;
#pragma unroll 1
  for (int ch = 0; ch < 8; ++ch) {
    __syncthreads();
#pragma unroll
    for (int it = 0; it < 8; ++it) {
      int v = tid + it * 256;
      *(f32x4*)(w1s + v * 4) =
          *(const f32x4*)(W1 + (size_t)(ch * 8 + (v >> 8)) * 1024 + (v & 255) * 4);
    }
    __syncthreads();
#pragma unroll 1
    for (int dl = 0; dl < 8; ++dl) {
      float xv = x[s * 64 + ch * 8 + dl];
#pragma unroll
      for (int j = 0; j < 16; ++j)
        c1[j] = fmaf(xv, w1s[dl * 1024 + j * 64 + lane], c1[j]);
    }
  }
#pragma unroll
  for (int j = 0; j < 16; ++j) c1[j] = __fadd_rn(c1[j], b1[j * 64 + lane]);

  float m1[16];
#pragma unroll
  for (int j = 0; j < 16; ++j) m1[j] = 0.0f;

#pragma unroll 1
  for (int t = 0; t < 25; ++t) {
#pragma unroll
    for (int j = 0; j < 16; ++j) {
      m1[j] = leaky(m1[j], c1[j]);
      u64 ball = __ballot(m1[j] > 1.0f);
      if (lane == 0) {
        masks[((size_t)t * 32 + 2 * j) * Sc + sl] = (u32)ball;
        masks[((size_t)t * 32 + 2 * j + 1) * Sc + sl] = (u32)(ball >> 32);
      }
    }
  }
}

// ---------------------------------------------------------------------------
// Phase B: cur2. ROUND-11 CHANGE: COLUMN-SPLIT waves. Unified-regfile model
// (r5-r10 data): occupancy = 512 / (arch VGPR + hidden AGPR accs).
//   r5 G=8 : 120 total -> 4 waves, 76% busy;  r8 G=16: 216 -> 2 waves, 64%.
// This kernel: 16 samples x 4 cols/lane per wave (one 256-column half).
// Accs 128->64, row load 1 dwordx4/row (halved), L2 traffic STAYS at G=16's
// 205 GB (row halves are disjoint; both half-waves co-resident in the same
// block stream the same k -> hot L2). Est. ~115 total regs -> 4 waves/SIMD
// with G=16 amortization: dominates both r5 and r8 points.
// 4-row buffer rotation at r8's proven ~280cy prefetch distance.
// Arithmetic unchanged (verified r5-r8): per-column ascending-k
// acc = fmaf(g, w, acc), g = wave-uniform (bit ? 1.0f : 0.0f):
// fma(1,w,c)=RN add = BLAS step, fma(0,w,c)=c exactly. Column chains are
// independent, so the wave split cannot change any rounding.
// ---------------------------------------------------------------------------
#define FOR16(M) M(0) M(1) M(2) M(3) M(4) M(5) M(6) M(7) \
                 M(8) M(9) M(10) M(11) M(12) M(13) M(14) M(15)
#define FOR16AB(M, a, b) M(0,a,b) M(1,a,b) M(2,a,b) M(3,a,b) M(4,a,b) M(5,a,b) \
                         M(6,a,b) M(7,a,b) M(8,a,b) M(9,a,b) M(10,a,b) M(11,a,b) \
                         M(12,a,b) M(13,a,b) M(14,a,b) M(15,a,b)

#define DECL_ACC(i) float a##i##_0 = 0.f, a##i##_1 = 0.f, a##i##_2 = 0.f, a##i##_3 = 0.f;

#define DECL_W(i) u32 w##i;
#define LOADW(i)  w##i = (u32)__builtin_amdgcn_readfirstlane((int)mp[i]);

#define GSR(i, R, MB) { const float g = (w##i & (MB)) ? 1.0f : 0.0f;    \
  a##i##_0 = fmaf(g, R[0], a##i##_0); a##i##_1 = fmaf(g, R[1], a##i##_1); \
  a##i##_2 = fmaf(g, R[2], a##i##_2); a##i##_3 = fmaf(g, R[3], a##i##_3); }

#define GROW(R, MB) FOR16AB(GSR, R, MB)

#define STOREH(i) { f32x4 o;                                            \
  o[0] = __fadd_rn(a##i##_0, bv[0]); o[1] = __fadd_rn(a##i##_1, bv[1]); \
  o[2] = __fadd_rn(a##i##_2, bv[2]); o[3] = __fadd_rn(a##i##_3, bv[3]); \
  *(f32x4*)(cur2 + ((size_t)(sl0 + i) * 25 + t) * 512 + lq) = o; }

__global__ __launch_bounds__(256) void k_cur2(
    const float* __restrict__ W2, const float* __restrict__ b2,
    const u32* __restrict__ masks, float* __restrict__ cur2, int Sc) {
  const int tid = threadIdx.x, lane = tid & 63, w = tid >> 6;
  const int wid = blockIdx.x * 4 + w;     // wave-task; grid = (Sc/16)*25/2 blks
  const int item = wid >> 1;              // (grp, t)
  const int half = wid & 1;               // which 256-column half
  const int grp = item / 25, t = item - grp * 25;
  const int sl0 = grp * 16;
  const int lq = half * 256 + lane * 4;   // column offset within a row

  FOR16(DECL_ACC)
  FOR16(DECL_W)

  const float* wp = W2 + lq;              // row k at wp + k*512 (one dwordx4)
  f32x4 rA = *(const f32x4*)(wp);
  f32x4 rB = *(const f32x4*)(wp + 512);
  f32x4 rC, rD;

#pragma unroll 1
  for (int kw = 0; kw < 32; ++kw) {
    const u32* mp = masks + ((size_t)t * 32 + kw) * Sc + sl0;
    FOR16(LOADW)                          // w0..w15 -> SGPRs
    const int kb = kw * 32;
#pragma unroll 1
    for (int k2 = 0; k2 < 32; k2 += 4) {
      const int k = kb + k2;
      // load rows k+2,k+3 while computing k,k+1 (~280cy prefetch distance)
      rC = *(const f32x4*)(wp + (size_t)(k + 2) * 512);
      rD = *(const f32x4*)(wp + (size_t)(k + 3) * 512);
      { const u32 mb = 1u << k2; GROW(rA, mb) }       // row k   (k ascending)
      { const u32 mb = 2u << k2; GROW(rB, mb) }       // row k+1
      const int k4 = (k + 4 < 1024) ? k + 4 : 1023;   // harmless tail clamp
      const int k5 = (k + 5 < 1024) ? k + 5 : 1023;
      rA = *(const f32x4*)(wp + (size_t)k4 * 512);
      rB = *(const f32x4*)(wp + (size_t)k5 * 512);
      { const u32 mb = 4u << k2; GROW(rC, mb) }       // row k+2
      { const u32 mb = 8u << k2; GROW(rD, mb) }       // row k+3
    }
  }

  const f32x4 bv = *(const f32x4*)(b2 + lq);
  FOR16(STOREH)
}

// ---------------------------------------------------------------------------
// Phase C: layers 2-3 recurrence off stored cur2 (exact f32 round-trip).
// (unchanged — verified)
// ---------------------------------------------------------------------------
__global__ __launch_bounds__(256) void k_tail(
    const float* __restrict__ cur2, const float* __restrict__ W3,
    const float* __restrict__ b3, float* __restrict__ out, int s0, int Sc) {
  __shared__ float w3s[512];
  const int tid = threadIdx.x, lane = tid & 63, w = tid >> 6;
  const int sl = blockIdx.x * 4 + w;
  for (int i = tid; i < 512; i += 256) w3s[i] = W3[i];
  __syncthreads();

  float m2[8];
#pragma unroll
  for (int j = 0; j < 8; ++j) m2[j] = 0.0f;
  float m3 = 0.0f;
  double s3 = 0.0;
  const float b3v = b3[0];
  const float* cp = cur2 + (size_t)sl * 25 * 512;

#pragma unroll 1
  for (int t = 0; t < 25; ++t) {
    u64 s2b[8];
#pragma unroll
    for (int j = 0; j < 8; ++j) {
      float cur = cp[t * 512 + j * 64 + lane];
      m2[j] = leaky(m2[j], cur);
      s2b[j] = __ballot(m2[j] > 1.0f);
    }
    if (lane == 0) {
      float c3 = 0.0f;
#pragma unroll 1
      for (int j = 0; j < 8; ++j) {
        u64 mm = s2b[j];
        const int nb = j * 64;
        if (mm) {
          int nn = __ffsll(mm) - 1;
          mm &= mm - 1;
          float wv = w3s[nb + nn];
          while (mm) {
            int n2 = __ffsll(mm) - 1;
            mm &= mm - 1;
            float wn = w3s[nb + n2];   // next load issued before dependent add
            c3 = __fadd_rn(c3, wv);
            wv = wn;
          }
          c3 = __fadd_rn(c3, wv);
        }
      }
      c3 = __fadd_rn(c3, b3v);
      m3 = leaky(m3, c3);
      s3 += (double)m3;
    }
  }
  if (lane == 0) {
    double z = s3 / 25.0;
    out[s0 + sl] = (float)(1.0 / (1.0 + exp(-z)));
  }
}

// ---------------------------------------------------------------------------
// Fallback: original verified single-kernel path (used if workspace too small)
// ---------------------------------------------------------------------------
__global__ __launch_bounds__(256) void k_snn(
    const float* __restrict__ x, const float* __restrict__ W1,
    const float* __restrict__ b1, const float* __restrict__ W2,
    const float* __restrict__ b2, const float* __restrict__ W3,
    const float* __restrict__ b3, float* __restrict__ out) {
  __shared__ float w1s[8 * 1024];
  __shared__ float w3s[512];
  __shared__ u32 spkm[4][32];
  const int tid = threadIdx.x, lane = tid & 63, w = tid >> 6;
  const size_t s = (size_t)blockIdx.x * 4 + w;

  for (int i = tid; i < 512; i += 256) w3s[i] = W3[i];

  float c1[16];
#pragma unroll
  for (int j = 0; j < 16; ++j) c1[j] = 0.0f;
#pragma unroll 1
  for (int ch = 0; ch < 8; ++ch) {
    __syncthreads();
#pragma unroll
    for (int it = 0; it < 8; ++it) {
      int v = tid + it * 256;
      *(f32x4*)(w1s + v * 4) =
          *(const f32x4*)(W1 + (size_t)(ch * 8 + (v >> 8)) * 1024 + (v & 255) * 4);
    }
    __syncthreads();
#pragma unroll 1
    for (int dl = 0; dl < 8; ++dl) {
      float xv = x[s * 64 + ch * 8 + dl];
#pragma unroll
      for (int j = 0; j < 16; ++j)
        c1[j] = fmaf(xv, w1s[dl * 1024 + j * 64 + lane], c1[j]);
    }
  }
#pragma unroll
  for (int j = 0; j < 16; ++j) c1[j] = __fadd_rn(c1[j], b1[j * 64 + lane]);

  float m1[16];
#pragma unroll
  for (int j = 0; j < 16; ++j) m1[j] = 0.0f;
  float m2[8];
#pragma unroll
  for (int j = 0; j < 8; ++j) m2[j] = 0.0f;
  float b2l[8];
#pragma unroll
  for (int j = 0; j < 8; ++j) b2l[j] = b2[j * 64 + lane];
  const float b3v = b3[0];
  float m3 = 0.0f;
  double s3 = 0.0;

#pragma unroll 1
  for (int t = 0; t < 25; ++t) {
#pragma unroll
    for (int j = 0; j < 16; ++j) {
      m1[j] = leaky(m1[j], c1[j]);
      u64 ball = __ballot(m1[j] > 1.0f);
      if (lane == 0) {
        spkm[w][2 * j]     = (u32)ball;
        spkm[w][2 * j + 1] = (u32)(ball >> 32);
      }
    }
    __syncthreads();

    float c2[8];
#pragma unroll
    for (int j = 0; j < 8; ++j) c2[j] = 0.0f;
#pragma unroll 1
    for (int kw = 0; kw < 32; ++kw) {
      u32 mask = spkm[w][kw];
      int kbase = kw * 32;
      while (mask) {
        int kk = __ffs(mask) - 1;
        mask &= mask - 1;
        const float* wr = W2 + (size_t)(kbase + kk) * 512;
#pragma unroll
        for (int j = 0; j < 8; ++j)
          c2[j] = __fadd_rn(c2[j], wr[j * 64 + lane]);
      }
    }
    u64 s2b[8];
#pragma unroll
    for (int j = 0; j < 8; ++j) {
      float cur = __fadd_rn(c2[j], b2l[j]);
      m2[j] = leaky(m2[j], cur);
      s2b[j] = __ballot(m2[j] > 1.0f);
    }

    if (lane == 0) {
      float c3 = 0.0f;
#pragma unroll 1
      for (int j = 0; j < 8; ++j) {
        u64 mm = s2b[j];
        int nb = j * 64;
        while (mm) {
          int nn = __ffsll(mm) - 1;
          mm &= mm - 1;
          c3 = __fadd_rn(c3, w3s[nb + nn]);
        }
      }
      c3 = __fadd_rn(c3, b3v);
      m3 = leaky(m3, c3);
      s3 += (double)m3;
    }
    __syncthreads();
  }

  if (lane == 0) {
    double z = s3 / 25.0;
    out[s] = (float)(1.0 / (1.0 + exp(-z)));
  }
}

extern "C" void kernel_launch(void* const* d_in, const int* in_sizes, int n_in,
                              void* d_out, int out_size, void* d_ws, size_t ws_size,
                              hipStream_t stream) {
  const float* x  = (const float*)d_in[0];
  const float* W1 = (const float*)d_in[1];
  const float* b1 = (const float*)d_in[2];
  const float* W2 = (const float*)d_in[3];
  const float* b2 = (const float*)d_in[4];
  const float* W3 = (const float*)d_in[5];
  const float* b3 = (const float*)d_in[6];
  float* out = (float*)d_out;

  // Per-sample workspace: masks 25*32*4 = 3200 B, cur2 25*512*4 = 51200 B.
  const long long per_sample = 54400;
  long long smax = (d_ws != nullptr) ? (long long)(ws_size / per_sample) : 0;
  long long scap = smax > 65536 ? 65536 : smax;
  int S = (int)(scap & ~63LL);

  if (S >= 256) {
    u32* masks = (u32*)d_ws;
    float* cur2 = (float*)((char*)d_ws + (size_t)S * 3200);
    for (int s0 = 0; s0 < 65536; s0 += S) {
      int Sc = (65536 - s0 < S) ? (65536 - s0) : S;
      hipLaunchKernelGGL(k_spk1, dim3(Sc / 4), dim3(256), 0, stream,
                         x, W1, b1, masks, s0, Sc);
      // (Sc/16) items * 25 steps * 2 column-half waves, 4 waves/block
      hipLaunchKernelGGL(k_cur2, dim3((Sc / 16) * 25 / 2), dim3(256), 0, stream,
                         W2, b2, masks, cur2, Sc);
      hipLaunchKernelGGL(k_tail, dim3(Sc / 4), dim3(256), 0, stream,
                         cur2, W3, b3, out, s0, Sc);
    }
  } else {
    hipLaunchKernelGGL(k_snn, dim3(16384), dim3(256), 0, stream,
                       x, W1, b1, W2, b2, W3, b3, out);
  }
}

// Round 12
// 26195.367 us; speedup vs baseline: 1.6581x; 1.0129x over previous
//
#include <hip/hip_runtime.h>

typedef unsigned int u32;
typedef unsigned long long u64;
typedef float f32x4 __attribute__((ext_vector_type(4)));

// np-bit-exact Leaky update: m' = f32(f32(f32(0.95f*m) + cur) - reset)
// reset from PREVIOUS mem; (mem-1>0) === (mem>1) exactly in f32 (Sterbenz).
__device__ __forceinline__ float leaky(float m, float cur) {
  float r = (m > 1.0f) ? 1.0f : 0.0f;
  return __fsub_rn(__fadd_rn(__fmul_rn(0.95f, m), cur), r);
}

// ---------------------------------------------------------------------------
// Phase A: cur1 (exact FMA chain, d ascending) + layer-1 sim; emit per-step
// spike bitmasks to global in [t][kw][sample] layout.  (unchanged — verified)
// ---------------------------------------------------------------------------
__global__ __launch_bounds__(256) void k_spk1(
    const float* __restrict__ x, const float* __restrict__ W1,
    const float* __restrict__ b1, u32* __restrict__ masks,
    int s0, int Sc) {
  __shared__ float w1s[8 * 1024];
  const int tid = threadIdx.x, lane = tid & 63, w = tid >> 6;
  const int sl = blockIdx.x * 4 + w;
  const size_t s = (size_t)s0 + sl;

  float c1[16];
#pragma unroll
  for (int j = 0; j < 16; ++j) c1[j] = 0.0f;
#pragma unroll 1
  for (int ch = 0; ch < 8; ++ch) {
    __syncthreads();
#pragma unroll
    for (int it = 0; it < 8; ++it) {
      int v = tid + it * 256;
      *(f32x4*)(w1s + v * 4) =
          *(const f32x4*)(W1 + (size_t)(ch * 8 + (v >> 8)) * 1024 + (v & 255) * 4);
    }
    __syncthreads();
#pragma unroll 1
    for (int dl = 0; dl < 8; ++dl) {
      float xv = x[s * 64 + ch * 8 + dl];
#pragma unroll
      for (int j = 0; j < 16; ++j)
        c1[j] = fmaf(xv, w1s[dl * 1024 + j * 64 + lane], c1[j]);
    }
  }
#pragma unroll
  for (int j = 0; j < 16; ++j) c1[j] = __fadd_rn(c1[j], b1[j * 64 + lane]);

  float m1[16];
#pragma unroll
  for (int j = 0; j < 16; ++j) m1[j] = 0.0f;

#pragma unroll 1
  for (int t = 0; t < 25; ++t) {
#pragma unroll
    for (int j = 0; j < 16; ++j) {
      m1[j] = leaky(m1[j], c1[j]);
      u64 ball = __ballot(m1[j] > 1.0f);
      if (lane == 0) {
        masks[((size_t)t * 32 + 2 * j) * Sc + sl] = (u32)ball;
        masks[((size_t)t * 32 + 2 * j + 1) * Sc + sl] = (u32)(ball >> 32);
      }
    }
  }
}

// ---------------------------------------------------------------------------
// Phase B: cur2, r11 column-split structure (16 samples x 4 cols/lane per
// wave; VGPR 56 arch + 64 AGPR accs -> 4 waves/SIMD, occ 40%).
// ROUND-12 CHANGE: SCALAR-DOMAIN GATES. r11's busy-time delta vs r8 showed
// the gate selects were lowered as v_cndmask (VALU): 2.5e8 instrs = 0.21 ms
// of the 1.53 ms busy. Here g is computed as integer SALU dataflow on the
// readfirstlane'd (uniform) mask word:  gb = ((w >> bit) & 1) * 0x3f800000;
// g = bitcast(gb)  -> s_lshr + s_and + s_mul (co-issued, free), g lives in
// an SGPR, and v_fma_f32 legally reads 1 SGPR operand -> gate cost 0 VALU.
// Exactness unchanged: g is exactly 1.0f or +0.0f; fmaf(+/-0,w,acc)=acc for
// all acc (sign-of-zero safe both ways); fma(1,w,c)=RN add = BLAS step;
// k strictly ascending; column chains independent of the wave split.
// ---------------------------------------------------------------------------
#define FOR16(M) M(0) M(1) M(2) M(3) M(4) M(5) M(6) M(7) \
                 M(8) M(9) M(10) M(11) M(12) M(13) M(14) M(15)
#define FOR16AB(M, a, b) M(0,a,b) M(1,a,b) M(2,a,b) M(3,a,b) M(4,a,b) M(5,a,b) \
                         M(6,a,b) M(7,a,b) M(8,a,b) M(9,a,b) M(10,a,b) M(11,a,b) \
                         M(12,a,b) M(13,a,b) M(14,a,b) M(15,a,b)

#define DECL_ACC(i) float a##i##_0 = 0.f, a##i##_1 = 0.f, a##i##_2 = 0.f, a##i##_3 = 0.f;

#define DECL_W(i) u32 w##i;
#define LOADW(i)  w##i = (u32)__builtin_amdgcn_readfirstlane((int)mp[i]);

// gate: uniform integer SALU select -> SGPR float; fma reads the SGPR.
#define GSR(i, R, BIT) {                                                 \
  const float g = __uint_as_float(((w##i >> (BIT)) & 1u) * 0x3f800000u); \
  a##i##_0 = fmaf(g, R[0], a##i##_0); a##i##_1 = fmaf(g, R[1], a##i##_1); \
  a##i##_2 = fmaf(g, R[2], a##i##_2); a##i##_3 = fmaf(g, R[3], a##i##_3); }

#define GROW(R, BIT) FOR16AB(GSR, R, BIT)

#define STOREH(i) { f32x4 o;                                            \
  o[0] = __fadd_rn(a##i##_0, bv[0]); o[1] = __fadd_rn(a##i##_1, bv[1]); \
  o[2] = __fadd_rn(a##i##_2, bv[2]); o[3] = __fadd_rn(a##i##_3, bv[3]); \
  *(f32x4*)(cur2 + ((size_t)(sl0 + i) * 25 + t) * 512 + lq) = o; }

__global__ __launch_bounds__(256) void k_cur2(
    const float* __restrict__ W2, const float* __restrict__ b2,
    const u32* __restrict__ masks, float* __restrict__ cur2, int Sc) {
  const int tid = threadIdx.x, lane = tid & 63, w = tid >> 6;
  const int wid = blockIdx.x * 4 + w;     // wave-task; grid = (Sc/16)*25/2 blks
  const int item = wid >> 1;              // (grp, t)
  const int half = wid & 1;               // which 256-column half
  const int grp = item / 25, t = item - grp * 25;
  const int sl0 = grp * 16;
  const int lq = half * 256 + lane * 4;   // column offset within a row

  FOR16(DECL_ACC)
  FOR16(DECL_W)

  const float* wp = W2 + lq;              // row k at wp + k*512 (one dwordx4)
  f32x4 rA = *(const f32x4*)(wp);
  f32x4 rB = *(const f32x4*)(wp + 512);
  f32x4 rC, rD;

#pragma unroll 1
  for (int kw = 0; kw < 32; ++kw) {
    const u32* mp = masks + ((size_t)t * 32 + kw) * Sc + sl0;
    FOR16(LOADW)                          // w0..w15 -> SGPRs
    const int kb = kw * 32;
#pragma unroll 1
    for (int k2 = 0; k2 < 32; k2 += 4) {
      const int k = kb + k2;
      // load rows k+2,k+3 while computing k,k+1 (~280cy prefetch distance)
      rC = *(const f32x4*)(wp + (size_t)(k + 2) * 512);
      rD = *(const f32x4*)(wp + (size_t)(k + 3) * 512);
      GROW(rA, k2)                                    // row k   (k ascending)
      GROW(rB, k2 + 1)                                // row k+1
      const int k4 = (k + 4 < 1024) ? k + 4 : 1023;   // harmless tail clamp
      const int k5 = (k + 5 < 1024) ? k + 5 : 1023;
      rA = *(const f32x4*)(wp + (size_t)k4 * 512);
      rB = *(const f32x4*)(wp + (size_t)k5 * 512);
      GROW(rC, k2 + 2)                                // row k+2
      GROW(rD, k2 + 3)                                // row k+3
    }
  }

  const f32x4 bv = *(const f32x4*)(b2 + lq);
  FOR16(STOREH)
}

// ---------------------------------------------------------------------------
// Phase C: layers 2-3 recurrence off stored cur2 (exact f32 round-trip).
// (unchanged — verified)
// ---------------------------------------------------------------------------
__global__ __launch_bounds__(256) void k_tail(
    const float* __restrict__ cur2, const float* __restrict__ W3,
    const float* __restrict__ b3, float* __restrict__ out, int s0, int Sc) {
  __shared__ float w3s[512];
  const int tid = threadIdx.x, lane = tid & 63, w = tid >> 6;
  const int sl = blockIdx.x * 4 + w;
  for (int i = tid; i < 512; i += 256) w3s[i] = W3[i];
  __syncthreads();

  float m2[8];
#pragma unroll
  for (int j = 0; j < 8; ++j) m2[j] = 0.0f;
  float m3 = 0.0f;
  double s3 = 0.0;
  const float b3v = b3[0];
  const float* cp = cur2 + (size_t)sl * 25 * 512;

#pragma unroll 1
  for (int t = 0; t < 25; ++t) {
    u64 s2b[8];
#pragma unroll
    for (int j = 0; j < 8; ++j) {
      float cur = cp[t * 512 + j * 64 + lane];
      m2[j] = leaky(m2[j], cur);
      s2b[j] = __ballot(m2[j] > 1.0f);
    }
    if (lane == 0) {
      float c3 = 0.0f;
#pragma unroll 1
      for (int j = 0; j < 8; ++j) {
        u64 mm = s2b[j];
        const int nb = j * 64;
        if (mm) {
          int nn = __ffsll(mm) - 1;
          mm &= mm - 1;
          float wv = w3s[nb + nn];
          while (mm) {
            int n2 = __ffsll(mm) - 1;
            mm &= mm - 1;
            float wn = w3s[nb + n2];   // next load issued before dependent add
            c3 = __fadd_rn(c3, wv);
            wv = wn;
          }
          c3 = __fadd_rn(c3, wv);
        }
      }
      c3 = __fadd_rn(c3, b3v);
      m3 = leaky(m3, c3);
      s3 += (double)m3;
    }
  }
  if (lane == 0) {
    double z = s3 / 25.0;
    out[s0 + sl] = (float)(1.0 / (1.0 + exp(-z)));
  }
}

// ---------------------------------------------------------------------------
// Fallback: original verified single-kernel path (used if workspace too small)
// ---------------------------------------------------------------------------
__global__ __launch_bounds__(256) void k_snn(
    const float* __restrict__ x, const float* __restrict__ W1,
    const float* __restrict__ b1, const float* __restrict__ W2,
    const float* __restrict__ b2, const float* __restrict__ W3,
    const float* __restrict__ b3, float* __restrict__ out) {
  __shared__ float w1s[8 * 1024];
  __shared__ float w3s[512];
  __shared__ u32 spkm[4][32];
  const int tid = threadIdx.x, lane = tid & 63, w = tid >> 6;
  const size_t s = (size_t)blockIdx.x * 4 + w;

  for (int i = tid; i < 512; i += 256) w3s[i] = W3[i];

  float c1[16];
#pragma unroll
  for (int j = 0; j < 16; ++j) c1[j] = 0.0f;
#pragma unroll 1
  for (int ch = 0; ch < 8; ++ch) {
    __syncthreads();
#pragma unroll
    for (int it = 0; it < 8; ++it) {
      int v = tid + it * 256;
      *(f32x4*)(w1s + v * 4) =
          *(const f32x4*)(W1 + (size_t)(ch * 8 + (v >> 8)) * 1024 + (v & 255) * 4);
    }
    __syncthreads();
#pragma unroll 1
    for (int dl = 0; dl < 8; ++dl) {
      float xv = x[s * 64 + ch * 8 + dl];
#pragma unroll
      for (int j = 0; j < 16; ++j)
        c1[j] = fmaf(xv, w1s[dl * 1024 + j * 64 + lane], c1[j]);
    }
  }
#pragma unroll
  for (int j = 0; j < 16; ++j) c1[j] = __fadd_rn(c1[j], b1[j * 64 + lane]);

  float m1[16];
#pragma unroll
  for (int j = 0; j < 16; ++j) m1[j] = 0.0f;
  float m2[8];
#pragma unroll
  for (int j = 0; j < 8; ++j) m2[j] = 0.0f;
  float b2l[8];
#pragma unroll
  for (int j = 0; j < 8; ++j) b2l[j] = b2[j * 64 + lane];
  const float b3v = b3[0];
  float m3 = 0.0f;
  double s3 = 0.0;

#pragma unroll 1
  for (int t = 0; t < 25; ++t) {
#pragma unroll
    for (int j = 0; j < 16; ++j) {
      m1[j] = leaky(m1[j], c1[j]);
      u64 ball = __ballot(m1[j] > 1.0f);
      if (lane == 0) {
        spkm[w][2 * j]     = (u32)ball;
        spkm[w][2 * j + 1] = (u32)(ball >> 32);
      }
    }
    __syncthreads();

    float c2[8];
#pragma unroll
    for (int j = 0; j < 8; ++j) c2[j] = 0.0f;
#pragma unroll 1
    for (int kw = 0; kw < 32; ++kw) {
      u32 mask = spkm[w][kw];
      int kbase = kw * 32;
      while (mask) {
        int kk = __ffs(mask) - 1;
        mask &= mask - 1;
        const float* wr = W2 + (size_t)(kbase + kk) * 512;
#pragma unroll
        for (int j = 0; j < 8; ++j)
          c2[j] = __fadd_rn(c2[j], wr[j * 64 + lane]);
      }
    }
    u64 s2b[8];
#pragma unroll
    for (int j = 0; j < 8; ++j) {
      float cur = __fadd_rn(c2[j], b2l[j]);
      m2[j] = leaky(m2[j], cur);
      s2b[j] = __ballot(m2[j] > 1.0f);
    }

    if (lane == 0) {
      float c3 = 0.0f;
#pragma unroll 1
      for (int j = 0; j < 8; ++j) {
        u64 mm = s2b[j];
        int nb = j * 64;
        while (mm) {
          int nn = __ffsll(mm) - 1;
          mm &= mm - 1;
          c3 = __fadd_rn(c3, w3s[nb + nn]);
        }
      }
      c3 = __fadd_rn(c3, b3v);
      m3 = leaky(m3, c3);
      s3 += (double)m3;
    }
    __syncthreads();
  }

  if (lane == 0) {
    double z = s3 / 25.0;
    out[s] = (float)(1.0 / (1.0 + exp(-z)));
  }
}

extern "C" void kernel_launch(void* const* d_in, const int* in_sizes, int n_in,
                              void* d_out, int out_size, void* d_ws, size_t ws_size,
                              hipStream_t stream) {
  const float* x  = (const float*)d_in[0];
  const float* W1 = (const float*)d_in[1];
  const float* b1 = (const float*)d_in[2];
  const float* W2 = (const float*)d_in[3];
  const float* b2 = (const float*)d_in[4];
  const float* W3 = (const float*)d_in[5];
  const float* b3 = (const float*)d_in[6];
  float* out = (float*)d_out;

  // Per-sample workspace: masks 25*32*4 = 3200 B, cur2 25*512*4 = 51200 B.
  const long long per_sample = 54400;
  long long smax = (d_ws != nullptr) ? (long long)(ws_size / per_sample) : 0;
  long long scap = smax > 65536 ? 65536 : smax;
  int S = (int)(scap & ~63LL);

  if (S >= 256) {
    u32* masks = (u32*)d_ws;
    float* cur2 = (float*)((char*)d_ws + (size_t)S * 3200);
    for (int s0 = 0; s0 < 65536; s0 += S) {
      int Sc = (65536 - s0 < S) ? (65536 - s0) : S;
      hipLaunchKernelGGL(k_spk1, dim3(Sc / 4), dim3(256), 0, stream,
                         x, W1, b1, masks, s0, Sc);
      // (Sc/16) items * 25 steps * 2 column-half waves, 4 waves/block
      hipLaunchKernelGGL(k_cur2, dim3((Sc / 16) * 25 / 2), dim3(256), 0, stream,
                         W2, b2, masks, cur2, Sc);
      hipLaunchKernelGGL(k_tail, dim3(Sc / 4), dim3(256), 0, stream,
                         cur2, W3, b3, out, s0, Sc);
    }
  } else {
    hipLaunchKernelGGL(k_snn, dim3(16384), dim3(256), 0, stream,
                       x, W1, b1, W2, b2, W3, b3, out);
  }
}